// Round 2
// baseline (4194.223 us; speedup 1.0000x reference)
//
#include <hip/hip_runtime.h>
#include <hip/hip_fp16.h>
#include <cstdint>
#include <cstddef>

#define T_STEPS 256
#define K_DIM 2048
#define ROWS_B 32        // rows per block; 256 blocks cover B=8192. Recurrence is block-local.
#define NWAVES 8
#define NT_W 16          // ntiles (16 cols) per wave: 256 cols/wave, 2048/block
#define REG_NT 4         // ntiles per wave resident in VGPRs
#define LDS_NT 4         // ntiles per wave resident in LDS (128 KB)
// ntiles 8..15 per wave are streamed from L2 every step (256 KB/block/step)

typedef _Float16 f16;
typedef _Float16 f16x8 __attribute__((ext_vector_type(8)));
typedef float f32x4 __attribute__((ext_vector_type(4)));

// LDS layout (static so the compiler sees true occupancy: 1 block/CU)
#define W1S_OFF 0        // 8 waves * 4 nt * 4 ks * 64 lanes * 16B = 131072
#define U_OFF   131072   // u [32 rows][64 cols] f16 swizzled = 4096
#define Y_OFF   135168   // y [2][32 rows][64 cols] f16 swizzled = 8192
#define PB_OFF  143360   // predbuf f32[8][32] = 1024
#define SMEM_BYTES 144384

// workspace: packed fp16 W1 only
#define W1P_BYTES (128 * 4 * 64 * 16)            // 524288

// Pack W1 [128][2048] f32 row-major into fp16 MFMA-B-fragment layout:
// w1p[((ntile*4 + ks)*64 + lane)*8 + i] = W1[ks*32 + (lane>>4)*8 + i][ntile*16 + (lane&15)]
__global__ void __launch_bounds__(64) prepack_w1(const float* __restrict__ W1,
                                                 f16* __restrict__ w1p) {
  int blk = blockIdx.x;            // 0..511 = ntile*4 + ks
  int ntile = blk >> 2, ks = blk & 3;
  int lane = threadIdx.x;
  int col = ntile * 16 + (lane & 15);
  int kb = ks * 32 + ((lane >> 4) << 3);
  f16x8 pk;
#pragma unroll
  for (int i = 0; i < 8; ++i) pk[i] = (f16)W1[(size_t)(kb + i) * K_DIM + col];
  ((f16x8*)w1p)[(ntile * 4 + ks) * 64 + lane] = pk;
}

__global__ void __launch_bounds__(512, 2)
__attribute__((amdgpu_waves_per_eu(2, 2)))
rnn_fused(const float* __restrict__ u, const float* __restrict__ y0,
          const f16* __restrict__ w1p, const float* __restrict__ b1,
          const float* __restrict__ w2, const float* __restrict__ b2,
          float* __restrict__ out)
{
  __shared__ __align__(16) char smem[SMEM_BYTES];
  f16x8* w1s     = (f16x8*)(smem + W1S_OFF);
  float* predbuf = (float*)(smem + PB_OFF);

  const int tid = threadIdx.x, lane = tid & 63, wave = tid >> 6;
  const int row0 = blockIdx.x * ROWS_B;
  const float b2v = b2[0];
  const f16x8* w1pv = (const f16x8*)w1p;
  const float TWO_L = 2.885390081777927f;   // 2*log2(e)

  // per-lane epilogue constants for this wave's 16 ntiles
  float b1x[NT_W], w2v[NT_W];
#pragma unroll
  for (int nt = 0; nt < NT_W; ++nt) {
    int col = wave * 256 + nt * 16 + (lane & 15);
    b1x[nt] = TWO_L * b1[col];
    w2v[nt] = w2[col];
  }

  // Cw = sum of ALL 2048 w2 entries (pred = Cw - 2*sum(w2*sigma) + b2)
  float Cw;
  {
    float s = 0.f;
#pragma unroll
    for (int i = 0; i < 32; ++i) s += w2[lane * 32 + i];
    s += __shfl_xor(s, 1);  s += __shfl_xor(s, 2);  s += __shfl_xor(s, 4);
    s += __shfl_xor(s, 8);  s += __shfl_xor(s, 16); s += __shfl_xor(s, 32);
    Cw = s;
  }

  // resident W1: ntiles 0..3 in VGPRs, 4..7 in LDS, 8..15 streamed per step
  f16x8 w1r[REG_NT * 4];
#pragma unroll
  for (int n = 0; n < REG_NT; ++n)
#pragma unroll
    for (int ks = 0; ks < 4; ++ks)
      w1r[n * 4 + ks] = w1pv[((wave * 16 + n) * 4 + ks) * 64 + lane];
#pragma unroll
  for (int i = 0; i < REG_NT * 4; ++i) asm volatile("" : "+v"(w1r[i]));

#pragma unroll
  for (int n = 0; n < LDS_NT; ++n)
#pragma unroll
    for (int ks = 0; ks < 4; ++ks)
      w1s[((wave * 4 + n) * 4 + ks) * 64 + lane] =
          w1pv[((wave * 16 + REG_NT + n) * 4 + ks) * 64 + lane];

  // init: waves 0-3 load y0, waves 4-7 load u_0 and prefetch u_1
  float4 up0, up1;
  if (tid < 256) {
    int r = tid >> 3, j0 = (tid & 7) * 8;
    const float4* yp = (const float4*)(y0 + (size_t)(row0 + r) * 64 + j0);
    float4 a = yp[0], c = yp[1];
    f16x8 pk;
    pk[0] = (f16)a.x; pk[1] = (f16)a.y; pk[2] = (f16)a.z; pk[3] = (f16)a.w;
    pk[4] = (f16)c.x; pk[5] = (f16)c.y; pk[6] = (f16)c.z; pk[7] = (f16)c.w;
    int byte = (r * 128 + j0 * 2) ^ ((r & 7) << 4);
    *(f16x8*)(smem + Y_OFF + byte) = pk;     // y[par=0]
  } else {
    int r = (tid - 256) >> 3, j0 = (tid & 7) * 8;
    const float4* p = (const float4*)(u + ((size_t)(row0 + r) * T_STEPS + 0) * 64 + j0);
    float4 a = p[0], c = p[1];
    f16x8 pk;
    pk[0] = (f16)a.x; pk[1] = (f16)a.y; pk[2] = (f16)a.z; pk[3] = (f16)a.w;
    pk[4] = (f16)c.x; pk[5] = (f16)c.y; pk[6] = (f16)c.z; pk[7] = (f16)c.w;
    int byte = (r * 128 + j0 * 2) ^ ((r & 7) << 4);
    *(f16x8*)(smem + U_OFF + byte) = pk;
    const float4* p1 = (const float4*)(u + ((size_t)(row0 + r) * T_STEPS + 1) * 64 + j0);
    up0 = p1[0]; up1 = p1[1];
  }
  __syncthreads();   // X valid for t=0

  for (int t = 0; t < T_STEPS; ++t) {
    const int par = t & 1;
    const char* ubase = smem + U_OFF;
    const char* ybase = smem + Y_OFF + par * 4096;

    // ---- A-fragments for 32 rows ----
    f16x8 af[2][4];
    {
      int koff = (lane >> 4) << 4;
#pragma unroll
      for (int mt = 0; mt < 2; ++mt) {
        int r = mt * 16 + (lane & 15);
        int base = r * 128 + koff, sw = (r & 7) << 4;
        af[mt][0] = *(const f16x8*)(ubase + (base ^ sw));
        af[mt][1] = *(const f16x8*)(ubase + ((base + 64) ^ sw));
        af[mt][2] = *(const f16x8*)(ybase + (base ^ sw));
        af[mt][3] = *(const f16x8*)(ybase + ((base + 64) ^ sw));
      }
    }

    f16x8 st0[4], st1[4];     // double-buffered streamed B-fragments
    float predp[2][4];
#pragma unroll
    for (int mt = 0; mt < 2; ++mt)
#pragma unroll
      for (int jj = 0; jj < 4; ++jj) predp[mt][jj] = 0.f;

    auto issue = [&](int s) {   // issue L2 loads for streamed ntile s
      f16x8* dst = ((s & 1) == 0) ? st0 : st1;
#pragma unroll
      for (int ks = 0; ks < 4; ++ks)
        dst[ks] = w1pv[((wave * 16 + s) * 4 + ks) * 64 + lane];
    };
    auto mfma_nt = [&](int n, f32x4* acc) {
      acc[0] = (f32x4){0.f, 0.f, 0.f, 0.f};
      acc[1] = (f32x4){0.f, 0.f, 0.f, 0.f};
#pragma unroll
      for (int ks = 0; ks < 4; ++ks) {
        f16x8 bf;
        if (n < REG_NT)      bf = w1r[n * 4 + ks];
        else if (n < 8)      bf = w1s[((wave * 4 + (n - REG_NT)) * 4 + ks) * 64 + lane];
        else if ((n & 1)==0) bf = st0[ks];
        else                 bf = st1[ks];
        acc[0] = __builtin_amdgcn_mfma_f32_16x16x32_f16(af[0][ks], bf, acc[0], 0, 0, 0);
        acc[1] = __builtin_amdgcn_mfma_f32_16x16x32_f16(af[1][ks], bf, acc[1], 0, 0, 0);
      }
    };
    // epilogue: S += w2 * rcp(1 + exp2(2L*s + 2L*b1));  h = 1 - 2*rcp
    auto epi = [&](int n, f32x4* acc) {
#pragma unroll
      for (int mt = 0; mt < 2; ++mt)
#pragma unroll
        for (int jj = 0; jj < 4; ++jj) {
          float e  = __builtin_amdgcn_exp2f(fmaf(TWO_L, acc[mt][jj], b1x[n]));
          float rr = __builtin_amdgcn_rcpf(1.0f + e);
          predp[mt][jj] = fmaf(w2v[n], rr, predp[mt][jj]);
        }
    };

    // ---- software-pipelined GEMM/epilogue over 16 ntiles; streamed loads
    //      issued >=2 groups ahead of use ----
    f32x4 accA[2], accB[2];
    issue(8); issue(9);
    mfma_nt(0, accA);
    mfma_nt(1, accB);
#pragma unroll
    for (int n = 2; n < 16; ++n) {
      if ((n & 1) == 0) { epi(n - 2, accA); mfma_nt(n, accA); }
      else              { epi(n - 2, accB); mfma_nt(n, accB); }
      if (n >= 8 && n + 2 < 16) issue(n + 2);   // after mfma(n) consumed its buffer
    }
    epi(14, accA);
    epi(15, accB);

    // wave reduce over the 16 col-lanes
#pragma unroll
    for (int mt = 0; mt < 2; ++mt)
#pragma unroll
      for (int jj = 0; jj < 4; ++jj) {
        float v = predp[mt][jj];
        v += __shfl_xor(v, 1); v += __shfl_xor(v, 2);
        v += __shfl_xor(v, 4); v += __shfl_xor(v, 8);
        if ((lane & 15) == 0)
          predbuf[wave * 32 + mt * 16 + ((lane >> 4) << 2) + jj] = v;
      }
    __syncthreads();   // [A] predbuf ready; X fully read for step t

    // ---- tail: waves 0-3 finalize pred + y-shift into y[par^1];
    //      waves 4-7 write u_{t+1} and prefetch u_{t+2} ----
    if (tid < 256) {
      int r3 = tid >> 3, j0 = (tid & 7) * 8;
      int sw3 = (r3 & 7) << 4;
      const char* yp = smem + Y_OFF + par * 4096;
      char*       yn = smem + Y_OFF + (par ^ 1) * 4096;
      f16x8 chB = *(const f16x8*)(yp + ((r3 * 128 + j0 * 2) ^ sw3));
      f16x8 nw;
      if (j0) {
        nw[0] = *(const f16*)(yp + ((r3 * 128 + j0 * 2 - 2) ^ sw3));
      } else {
        float own = 0.f;
#pragma unroll
        for (int w = 0; w < NWAVES; ++w) own += predbuf[w * 32 + r3];
        float ps = fmaf(-2.0f, own, Cw) + b2v;
        out[(size_t)(row0 + r3) * T_STEPS + t] = ps;
        nw[0] = (f16)ps;
      }
#pragma unroll
      for (int i = 1; i < 8; ++i) nw[i] = chB[i - 1];
      *(f16x8*)(yn + ((r3 * 128 + j0 * 2) ^ sw3)) = nw;
    } else {
      int r3 = (tid - 256) >> 3, j0 = (tid & 7) * 8;
      int sw3 = (r3 & 7) << 4;
      if (t + 1 < T_STEPS) {
        f16x8 pk;
        pk[0] = (f16)up0.x; pk[1] = (f16)up0.y; pk[2] = (f16)up0.z; pk[3] = (f16)up0.w;
        pk[4] = (f16)up1.x; pk[5] = (f16)up1.y; pk[6] = (f16)up1.z; pk[7] = (f16)up1.w;
        *(f16x8*)(smem + U_OFF + ((r3 * 128 + j0 * 2) ^ sw3)) = pk;
      }
      if (t + 2 < T_STEPS) {
        const float4* p =
            (const float4*)(u + ((size_t)(row0 + r3) * T_STEPS + t + 2) * 64 + j0);
        up0 = p[0]; up1 = p[1];
      }
    }
    __syncthreads();   // [C] X valid for step t+1
  }
}

extern "C" void kernel_launch(void* const* d_in, const int* in_sizes, int n_in,
                              void* d_out, int out_size, void* d_ws, size_t ws_size,
                              hipStream_t stream) {
  const float* u  = (const float*)d_in[0];
  const float* y0 = (const float*)d_in[1];
  const float* W1 = (const float*)d_in[2];
  const float* b1 = (const float*)d_in[3];
  const float* W2 = (const float*)d_in[4];
  const float* b2 = (const float*)d_in[5];

  f16* w1p = (f16*)d_ws;

  prepack_w1<<<512, 64, 0, stream>>>(W1, w1p);

  rnn_fused<<<256, 512, 0, stream>>>(u, y0, w1p, b1, W2, b2, (float*)d_out);
}